// Round 7
// baseline (175.749 us; speedup 1.0000x reference)
//
#include <hip/hip_runtime.h>
#include <hip/hip_bf16.h>

#define T 512
#define C 256
#define D12 12
#define HID 32
#define BN_EPS 1e-5f
#define SCALE 0.0625f

typedef __attribute__((ext_vector_type(8))) short bf16x8;
typedef __attribute__((ext_vector_type(4))) float f32x4;

static __device__ __forceinline__ short f2bf(float f) {
    __hip_bfloat16 h = __float2bfloat16(f);
    return *reinterpret_cast<short*>(&h);
}

// ---- k1m: fused TPR MLP + col-max + bias + w_qkv transpose ----------------
// blocks 0..1023: one per (b,s). Layer-1 A-frags loaded straight from global
// (no r staging LDS, 2 barriers/iter instead of 3, next-iter r prefetched in
// registers across the layer-2 MFMA block).
// blocks 1024..1071: w_qkv [256][768] f32 -> wT [768][256] bf16 (tiled).
__global__ __launch_bounds__(256) void k1m_mlp_bias(
    const float* __restrict__ x, const float* __restrict__ r,
    const float* __restrict__ w1, const float* __restrict__ b1,
    const float* __restrict__ g1, const float* __restrict__ be1,
    const float* __restrict__ m1, const float* __restrict__ v1,
    const float* __restrict__ w2, const float* __restrict__ b2,
    const float* __restrict__ g2, const float* __restrict__ be2,
    const float* __restrict__ m2, const float* __restrict__ v2,
    const float* __restrict__ wqkv,
    short* __restrict__ xbb, short* __restrict__ wT)
{
    __shared__ short h1sh[64 * 40];   // [t][h] bf16, stride 40
    __shared__ float biassh[C];
    __shared__ short tsh[64 * 66];

    const int tid  = threadIdx.x;
    const int blk  = blockIdx.x;

    if (blk >= 1024) {   // ---- w_qkv transpose path ----
        const int bid2 = blk - 1024;
        const int d0 = (bid2 / 12) * 64;
        const int e0 = (bid2 % 12) * 64;
        #pragma unroll
        for (int i = 0; i < 16; ++i) {
            int idx = i * 256 + tid;
            int di = idx >> 6, ej = idx & 63;
            tsh[di * 66 + ej] = f2bf(wqkv[(size_t)(d0 + di) * 768 + e0 + ej]);
        }
        __syncthreads();
        #pragma unroll
        for (int i = 0; i < 16; ++i) {
            int idx = i * 256 + tid;
            int ei = idx >> 6, dj = idx & 63;
            wT[(size_t)(e0 + ei) * 256 + d0 + dj] = tsh[dj * 66 + ei];
        }
        return;
    }

    const int lane = tid & 63;
    const int wave = tid >> 6;
    const int quad = lane >> 4;
    const int mrow = lane & 15;

    // layer1 B-frags + init consts, straight from global (L2-resident)
    bf16x8 b1f[2];
    float  c1r[2];
    #pragma unroll
    for (int nt = 0; nt < 2; ++nt) {
        int h = nt * 16 + mrow;
        float s1 = g1[h] * rsqrtf(v1[h] + BN_EPS);
        c1r[nt] = (b1[h] - m1[h]) * s1 + be1[h];
        #pragma unroll
        for (int j = 0; j < 8; ++j) {
            int k = quad * 8 + j;
            b1f[nt][j] = (k < D12) ? f2bf(w1[k * HID + h] * s1) : (short)0;
        }
    }

    // layer2 B-frags: w2 with BN2 scale folded; wave owns cols 64w..64w+63
    bf16x8 bfrag[4];
    float  c2r[4];
    #pragma unroll
    for (int ct = 0; ct < 4; ++ct) {
        int c = wave * 64 + ct * 16 + mrow;
        float s2 = g2[c] * rsqrtf(v2[c] + BN_EPS);
        c2r[ct] = (b2[c] - m2[c]) * s2 + be2[c];
        #pragma unroll
        for (int j = 0; j < 8; ++j) {
            int k = quad * 8 + j;
            bfrag[ct][j] = f2bf(w2[k * C + c] * s2);
        }
    }

    const float* rbase = r + (size_t)blk * T * D12;
    float maxv[4] = {0.f, 0.f, 0.f, 0.f};   // relu output >= 0

    // r-row prefetch (lane's layer1 A-frag source): quad0 -> k0..7,
    // quad1 -> k8..11, quads 2/3 -> zero.
    float v[8];
    #pragma unroll
    for (int j = 0; j < 8; ++j) v[j] = 0.f;
    {
        const float* rrow = rbase + (size_t)(wave * 16 + mrow) * D12;
        if (quad == 0) {
            float4 p0 = *reinterpret_cast<const float4*>(rrow);
            float4 p1 = *reinterpret_cast<const float4*>(rrow + 4);
            v[0] = p0.x; v[1] = p0.y; v[2] = p0.z; v[3] = p0.w;
            v[4] = p1.x; v[5] = p1.y; v[6] = p1.z; v[7] = p1.w;
        } else if (quad == 1) {
            float4 p2 = *reinterpret_cast<const float4*>(rrow + 8);
            v[0] = p2.x; v[1] = p2.y; v[2] = p2.z; v[3] = p2.w;
        }
    }

    for (int it = 0; it < 8; ++it) {
        // layer1: A from registers, D[t'=quad*4+rg][h'=mrow] -> h1sh
        bf16x8 af;
        #pragma unroll
        for (int j = 0; j < 8; ++j) af[j] = f2bf(v[j]);
        #pragma unroll
        for (int nt = 0; nt < 2; ++nt) {
            f32x4 a = {c1r[nt], c1r[nt], c1r[nt], c1r[nt]};
            a = __builtin_amdgcn_mfma_f32_16x16x32_bf16(af, b1f[nt], a, 0, 0, 0);
            #pragma unroll
            for (int rg = 0; rg < 4; ++rg)
                h1sh[(wave * 16 + quad * 4 + rg) * 40 + nt * 16 + mrow] =
                    f2bf(fmaxf(a[rg], 0.f));
        }
        // prefetch next iteration's r row (completes during layer-2 MFMAs)
        if (it < 7) {
            const float* rrow = rbase + (size_t)((it + 1) * 64 + wave * 16 + mrow) * D12;
            if (quad == 0) {
                float4 p0 = *reinterpret_cast<const float4*>(rrow);
                float4 p1 = *reinterpret_cast<const float4*>(rrow + 4);
                v[0] = p0.x; v[1] = p0.y; v[2] = p0.z; v[3] = p0.w;
                v[4] = p1.x; v[5] = p1.y; v[6] = p1.z; v[7] = p1.w;
            } else if (quad == 1) {
                float4 p2 = *reinterpret_cast<const float4*>(rrow + 8);
                v[0] = p2.x; v[1] = p2.y; v[2] = p2.z; v[3] = p2.w;
            }
        }
        __syncthreads();
        // layer2: A = all 64 h1 rows from LDS, 16 MFMAs, fused max epilogue
        #pragma unroll
        for (int rt = 0; rt < 4; ++rt) {
            bf16x8 a2 = *reinterpret_cast<const bf16x8*>(
                &h1sh[(rt * 16 + mrow) * 40 + quad * 8]);
            #pragma unroll
            for (int ct = 0; ct < 4; ++ct) {
                f32x4 acc = {c2r[ct], c2r[ct], c2r[ct], c2r[ct]};
                acc = __builtin_amdgcn_mfma_f32_16x16x32_bf16(a2, bfrag[ct], acc, 0, 0, 0);
                #pragma unroll
                for (int rg = 0; rg < 4; ++rg)
                    maxv[ct] = fmaxf(maxv[ct], acc[rg]);
            }
        }
        __syncthreads();   // h1sh safe for next iteration
    }

    #pragma unroll
    for (int ct = 0; ct < 4; ++ct) {
        float m = maxv[ct];
        m = fmaxf(m, __shfl_xor(m, 16));
        m = fmaxf(m, __shfl_xor(m, 32));
        if (quad == 0) biassh[wave * 64 + ct * 16 + mrow] = m;
    }
    __syncthreads();
    xbb[(size_t)blk * C + tid] = f2bf(x[(size_t)blk * C + tid] + biassh[tid]);
}

// ---- k2m: qkv GEMM; q/k -> qbf (q pre-scaled); v-blocks -> vT; zero cnt ---
__global__ __launch_bounds__(256) void k2m_qkv(
    const short* __restrict__ xbb, const short* __restrict__ wT,
    short* __restrict__ qbf, short* __restrict__ vT, int* __restrict__ cnt)
{
    __shared__ short tsh[64 * 66];
    const int tid  = threadIdx.x;
    const int lane = tid & 63;
    const int wave = tid >> 6;
    const int quad = lane >> 4;
    const int mrow = lane & 15;
    const int rb = blockIdx.x / 12;
    const int cb = blockIdx.x % 12;
    const int row0 = rb * 64 + wave * 16;
    const int col0 = cb * 64;
    const float osc = (cb < 4) ? SCALE : 1.0f;

    if (blockIdx.x == 0 && tid < 64) cnt[tid] = 0;   // split-K counters for k3c

    f32x4 acc[4];
    #pragma unroll
    for (int ct = 0; ct < 4; ++ct) acc[ct] = (f32x4){0.f, 0.f, 0.f, 0.f};

    for (int ks = 0; ks < 8; ++ks) {
        bf16x8 afrag = *reinterpret_cast<const bf16x8*>(
            &xbb[(size_t)(row0 + mrow) * 256 + ks * 32 + quad * 8]);
        #pragma unroll
        for (int ct = 0; ct < 4; ++ct) {
            bf16x8 bfrag = *reinterpret_cast<const bf16x8*>(
                &wT[(size_t)(col0 + ct * 16 + mrow) * 256 + ks * 32 + quad * 8]);
            acc[ct] = __builtin_amdgcn_mfma_f32_16x16x32_bf16(afrag, bfrag, acc[ct], 0, 0, 0);
        }
    }

    if (cb < 8) {   // q, k: direct store to qbf
        #pragma unroll
        for (int ct = 0; ct < 4; ++ct)
            #pragma unroll
            for (int rg = 0; rg < 4; ++rg)
                qbf[(size_t)(row0 + quad * 4 + rg) * 768 + col0 + ct * 16 + mrow] =
                    f2bf(acc[ct][rg] * osc);
    } else {        // v: transpose 64x64 tile through LDS, store to vT[b][d][s]
        #pragma unroll
        for (int ct = 0; ct < 4; ++ct)
            #pragma unroll
            for (int rg = 0; rg < 4; ++rg)
                tsh[(wave * 16 + quad * 4 + rg) * 66 + ct * 16 + mrow] = f2bf(acc[ct][rg]);
        __syncthreads();
        const int b  = rb >> 3;
        const int s0 = (rb & 7) * 64;
        const int dg = (cb - 8) * 64;
        #pragma unroll
        for (int i = 0; i < 16; ++i) {
            int idx = i * 256 + tid;
            int ci = idx >> 6, rj = idx & 63;
            vT[((size_t)(b * 256 + dg + ci)) * 512 + s0 + rj] = tsh[rj * 66 + ci];
        }
    }
}

// ---- k3c: flash attention partials + split-K last-block combine -----------
__global__ __launch_bounds__(256) void k3c_attn(
    const short* __restrict__ qbf, const short* __restrict__ vT,
    float* __restrict__ po, float2* __restrict__ stats,
    int* __restrict__ cnt, float* __restrict__ out)
{
    __shared__ float msh[4][16];
    __shared__ float lsh[4][16];
    __shared__ short psh[16 * 136];
    __shared__ int lastsh;
    const int tid  = threadIdx.x;
    const int lane = tid & 63;
    const int wave = tid >> 6;
    const int quad = lane >> 4;
    const int mrow = lane & 15;
    const int qt = blockIdx.x >> 2;
    const int sc = blockIdx.x & 3;
    const int b  = qt >> 5;
    const int row0  = qt * 16;
    const int srow0 = b * 512 + sc * 128;

    bf16x8 qf[8];
    {
        const short* qrow = qbf + (size_t)(row0 + mrow) * 768;
        #pragma unroll
        for (int ks = 0; ks < 8; ++ks)
            qf[ks] = *reinterpret_cast<const bf16x8*>(qrow + ks * 32 + quad * 8);
    }

    f32x4 S[2];
    #pragma unroll
    for (int st = 0; st < 2; ++st) {
        f32x4 acc = {0.f, 0.f, 0.f, 0.f};
        const short* krow = qbf + (size_t)(srow0 + wave * 32 + st * 16 + mrow) * 768 + 256;
        #pragma unroll
        for (int ks = 0; ks < 8; ++ks) {
            bf16x8 kf = *reinterpret_cast<const bf16x8*>(krow + ks * 32 + quad * 8);
            acc = __builtin_amdgcn_mfma_f32_16x16x32_bf16(qf[ks], kf, acc, 0, 0, 0);
        }
        S[st] = acc;
    }

    float mx[4];
    #pragma unroll
    for (int rg = 0; rg < 4; ++rg) mx[rg] = fmaxf(S[0][rg], S[1][rg]);
    #pragma unroll
    for (int off = 1; off < 16; off <<= 1)
        #pragma unroll
        for (int rg = 0; rg < 4; ++rg) mx[rg] = fmaxf(mx[rg], __shfl_xor(mx[rg], off));
    if (mrow == 0)
        #pragma unroll
        for (int rg = 0; rg < 4; ++rg) msh[wave][quad * 4 + rg] = mx[rg];
    __syncthreads();

    float M[4], sm[4];
    #pragma unroll
    for (int rg = 0; rg < 4; ++rg) {
        int m = quad * 4 + rg;
        M[rg] = fmaxf(fmaxf(msh[0][m], msh[1][m]), fmaxf(msh[2][m], msh[3][m]));
    }
    float ex[2][4];
    #pragma unroll
    for (int st = 0; st < 2; ++st)
        #pragma unroll
        for (int rg = 0; rg < 4; ++rg) ex[st][rg] = __expf(S[st][rg] - M[rg]);
    #pragma unroll
    for (int rg = 0; rg < 4; ++rg) sm[rg] = ex[0][rg] + ex[1][rg];
    #pragma unroll
    for (int off = 1; off < 16; off <<= 1)
        #pragma unroll
        for (int rg = 0; rg < 4; ++rg) sm[rg] += __shfl_xor(sm[rg], off);
    if (mrow == 0)
        #pragma unroll
        for (int rg = 0; rg < 4; ++rg) lsh[wave][quad * 4 + rg] = sm[rg];
    #pragma unroll
    for (int st = 0; st < 2; ++st)
        #pragma unroll
        for (int rg = 0; rg < 4; ++rg)
            psh[(quad * 4 + rg) * 136 + wave * 32 + st * 16 + mrow] = f2bf(ex[st][rg]);
    __syncthreads();

    if (wave == 0 && mrow == 0) {
        #pragma unroll
        for (int rg = 0; rg < 4; ++rg) {
            int m = quad * 4 + rg;
            float l = lsh[0][m] + lsh[1][m] + lsh[2][m] + lsh[3][m];
            stats[blockIdx.x * 16 + m] = make_float2(M[rg], l);
        }
    }

    const short* vbase = vT + (size_t)b * 256 * 512;
    f32x4 o[4];
    #pragma unroll
    for (int i = 0; i < 4; ++i) o[i] = (f32x4){0.f, 0.f, 0.f, 0.f};
    #pragma unroll
    for (int ks = 0; ks < 4; ++ks) {
        bf16x8 pf = *reinterpret_cast<const bf16x8*>(&psh[mrow * 136 + ks * 32 + quad * 8]);
        #pragma unroll
        for (int i = 0; i < 4; ++i) {
            int d0 = (wave * 4 + i) * 16;
            bf16x8 vf = *reinterpret_cast<const bf16x8*>(
                vbase + (size_t)(d0 + mrow) * 512 + sc * 128 + ks * 32 + quad * 8);
            o[i] = __builtin_amdgcn_mfma_f32_16x16x32_bf16(pf, vf, o[i], 0, 0, 0);
        }
    }
    #pragma unroll
    for (int i = 0; i < 4; ++i)
        #pragma unroll
        for (int rg = 0; rg < 4; ++rg)
            po[((size_t)blockIdx.x * 16 + quad * 4 + rg) * 256 + (wave * 4 + i) * 16 + mrow] =
                o[i][rg];

    // ---- split-K combine: last arriving block for this qt does k3b's work --
    __threadfence();            // release po/stats (device scope)
    __syncthreads();
    if (tid == 0) lastsh = (atomicAdd(&cnt[qt], 1) == 3);
    __syncthreads();
    if (!lastsh) return;
    __threadfence();            // acquire other blocks' po/stats

    for (int m = 0; m < 16; ++m) {
        float2 s0 = stats[(qt * 4 + 0) * 16 + m];
        float2 s1 = stats[(qt * 4 + 1) * 16 + m];
        float2 s2 = stats[(qt * 4 + 2) * 16 + m];
        float2 s3 = stats[(qt * 4 + 3) * 16 + m];
        float Mm = fmaxf(fmaxf(s0.x, s1.x), fmaxf(s2.x, s3.x));
        float a0 = __expf(s0.x - Mm), a1 = __expf(s1.x - Mm);
        float a2 = __expf(s2.x - Mm), a3 = __expf(s3.x - Mm);
        float inv = 1.f / (a0 * s0.y + a1 * s1.y + a2 * s2.y + a3 * s3.y);
        float accv = a0 * po[((size_t)(qt * 4 + 0) * 16 + m) * 256 + tid]
                   + a1 * po[((size_t)(qt * 4 + 1) * 16 + m) * 256 + tid]
                   + a2 * po[((size_t)(qt * 4 + 2) * 16 + m) * 256 + tid]
                   + a3 * po[((size_t)(qt * 4 + 3) * 16 + m) * 256 + tid];
        out[(size_t)(row0 + m) * 256 + tid] = accv * inv;
    }
}

extern "C" void kernel_launch(void* const* d_in, const int* in_sizes, int n_in,
                              void* d_out, int out_size, void* d_ws, size_t ws_size,
                              hipStream_t stream) {
    const float* x    = (const float*)d_in[0];
    const float* r    = (const float*)d_in[1];
    const float* w1   = (const float*)d_in[2];
    const float* b1   = (const float*)d_in[3];
    const float* g1   = (const float*)d_in[4];
    const float* be1  = (const float*)d_in[5];
    const float* m1   = (const float*)d_in[6];
    const float* v1   = (const float*)d_in[7];
    const float* w2   = (const float*)d_in[8];
    const float* b2   = (const float*)d_in[9];
    const float* g2   = (const float*)d_in[10];
    const float* be2  = (const float*)d_in[11];
    const float* m2   = (const float*)d_in[12];
    const float* v2   = (const float*)d_in[13];
    const float* wqkv = (const float*)d_in[14];
    float* out = (float*)d_out;

    // ws layout (bytes):
    //   qbf   [1024*768] bf16  @ 0
    //   vT    [2*256*512] bf16 @ 1,572,864
    //   xbb   [1024*256] bf16  @ 2,097,152
    //   wT    [768*256] bf16   @ 2,621,440
    //   po    [256*16*256] f32 @ 3,014,656
    //   stats [256*16] float2  @ 7,208,960
    //   cnt   [64] int         @ 7,241,728
    char* ws = (char*)d_ws;
    short*  qbf   = (short*)(ws);
    short*  vT    = (short*)(ws + 1572864);
    short*  xbb   = (short*)(ws + 2097152);
    short*  wT    = (short*)(ws + 2621440);
    float*  po    = (float*)(ws + 3014656);
    float2* stats = (float2*)(ws + 7208960);
    int*    cnt   = (int*)(ws + 7241728);

    k1m_mlp_bias<<<1072, 256, 0, stream>>>(x, r, w1, b1, g1, be1, m1, v1,
                                           w2, b2, g2, be2, m2, v2, wqkv, xbb, wT);
    k2m_qkv<<<192, 256, 0, stream>>>(xbb, wT, qbf, vT, cnt);
    k3c_attn<<<256, 256, 0, stream>>>(qbf, vT, po, stats, cnt, out);
}

// Round 8
// 131.281 us; speedup vs baseline: 1.3387x; 1.3387x over previous
//
#include <hip/hip_runtime.h>
#include <hip/hip_bf16.h>

#define T 512
#define C 256
#define D12 12
#define HID 32
#define BN_EPS 1e-5f
#define SCALE 0.0625f

typedef __attribute__((ext_vector_type(8))) short bf16x8;
typedef __attribute__((ext_vector_type(4))) float f32x4;

static __device__ __forceinline__ short f2bf(float f) {
    __hip_bfloat16 h = __float2bfloat16(f);
    return *reinterpret_cast<short*>(&h);
}

// ---- k1m: fused TPR MLP + col-max + bias + w_qkv transpose (R6-proven) ----
// blocks 0..1023: one per (b,s). Layer-1 A-frags loaded straight from global,
// 2 barriers/iter, next-iter r prefetched in registers across layer-2 MFMAs.
// blocks 1024..1071: w_qkv [256][768] f32 -> wT [768][256] bf16 (tiled).
__global__ __launch_bounds__(256) void k1m_mlp_bias(
    const float* __restrict__ x, const float* __restrict__ r,
    const float* __restrict__ w1, const float* __restrict__ b1,
    const float* __restrict__ g1, const float* __restrict__ be1,
    const float* __restrict__ m1, const float* __restrict__ v1,
    const float* __restrict__ w2, const float* __restrict__ b2,
    const float* __restrict__ g2, const float* __restrict__ be2,
    const float* __restrict__ m2, const float* __restrict__ v2,
    const float* __restrict__ wqkv,
    short* __restrict__ xbb, short* __restrict__ wT)
{
    __shared__ short h1sh[64 * 40];   // [t][h] bf16, stride 40
    __shared__ float biassh[C];
    __shared__ short tsh[64 * 66];

    const int tid  = threadIdx.x;
    const int blk  = blockIdx.x;

    if (blk >= 1024) {   // ---- w_qkv transpose path ----
        const int bid2 = blk - 1024;
        const int d0 = (bid2 / 12) * 64;
        const int e0 = (bid2 % 12) * 64;
        #pragma unroll
        for (int i = 0; i < 16; ++i) {
            int idx = i * 256 + tid;
            int di = idx >> 6, ej = idx & 63;
            tsh[di * 66 + ej] = f2bf(wqkv[(size_t)(d0 + di) * 768 + e0 + ej]);
        }
        __syncthreads();
        #pragma unroll
        for (int i = 0; i < 16; ++i) {
            int idx = i * 256 + tid;
            int ei = idx >> 6, dj = idx & 63;
            wT[(size_t)(e0 + ei) * 256 + d0 + dj] = tsh[dj * 66 + ei];
        }
        return;
    }

    const int lane = tid & 63;
    const int wave = tid >> 6;
    const int quad = lane >> 4;
    const int mrow = lane & 15;

    bf16x8 b1f[2];
    float  c1r[2];
    #pragma unroll
    for (int nt = 0; nt < 2; ++nt) {
        int h = nt * 16 + mrow;
        float s1 = g1[h] * rsqrtf(v1[h] + BN_EPS);
        c1r[nt] = (b1[h] - m1[h]) * s1 + be1[h];
        #pragma unroll
        for (int j = 0; j < 8; ++j) {
            int k = quad * 8 + j;
            b1f[nt][j] = (k < D12) ? f2bf(w1[k * HID + h] * s1) : (short)0;
        }
    }

    bf16x8 bfrag[4];
    float  c2r[4];
    #pragma unroll
    for (int ct = 0; ct < 4; ++ct) {
        int c = wave * 64 + ct * 16 + mrow;
        float s2 = g2[c] * rsqrtf(v2[c] + BN_EPS);
        c2r[ct] = (b2[c] - m2[c]) * s2 + be2[c];
        #pragma unroll
        for (int j = 0; j < 8; ++j) {
            int k = quad * 8 + j;
            bfrag[ct][j] = f2bf(w2[k * C + c] * s2);
        }
    }

    const float* rbase = r + (size_t)blk * T * D12;
    float maxv[4] = {0.f, 0.f, 0.f, 0.f};

    float v[8];
    #pragma unroll
    for (int j = 0; j < 8; ++j) v[j] = 0.f;
    {
        const float* rrow = rbase + (size_t)(wave * 16 + mrow) * D12;
        if (quad == 0) {
            float4 p0 = *reinterpret_cast<const float4*>(rrow);
            float4 p1 = *reinterpret_cast<const float4*>(rrow + 4);
            v[0] = p0.x; v[1] = p0.y; v[2] = p0.z; v[3] = p0.w;
            v[4] = p1.x; v[5] = p1.y; v[6] = p1.z; v[7] = p1.w;
        } else if (quad == 1) {
            float4 p2 = *reinterpret_cast<const float4*>(rrow + 8);
            v[0] = p2.x; v[1] = p2.y; v[2] = p2.z; v[3] = p2.w;
        }
    }

    for (int it = 0; it < 8; ++it) {
        bf16x8 af;
        #pragma unroll
        for (int j = 0; j < 8; ++j) af[j] = f2bf(v[j]);
        #pragma unroll
        for (int nt = 0; nt < 2; ++nt) {
            f32x4 a = {c1r[nt], c1r[nt], c1r[nt], c1r[nt]};
            a = __builtin_amdgcn_mfma_f32_16x16x32_bf16(af, b1f[nt], a, 0, 0, 0);
            #pragma unroll
            for (int rg = 0; rg < 4; ++rg)
                h1sh[(wave * 16 + quad * 4 + rg) * 40 + nt * 16 + mrow] =
                    f2bf(fmaxf(a[rg], 0.f));
        }
        if (it < 7) {
            const float* rrow = rbase + (size_t)((it + 1) * 64 + wave * 16 + mrow) * D12;
            if (quad == 0) {
                float4 p0 = *reinterpret_cast<const float4*>(rrow);
                float4 p1 = *reinterpret_cast<const float4*>(rrow + 4);
                v[0] = p0.x; v[1] = p0.y; v[2] = p0.z; v[3] = p0.w;
                v[4] = p1.x; v[5] = p1.y; v[6] = p1.z; v[7] = p1.w;
            } else if (quad == 1) {
                float4 p2 = *reinterpret_cast<const float4*>(rrow + 8);
                v[0] = p2.x; v[1] = p2.y; v[2] = p2.z; v[3] = p2.w;
            }
        }
        __syncthreads();
        #pragma unroll
        for (int rt = 0; rt < 4; ++rt) {
            bf16x8 a2 = *reinterpret_cast<const bf16x8*>(
                &h1sh[(rt * 16 + mrow) * 40 + quad * 8]);
            #pragma unroll
            for (int ct = 0; ct < 4; ++ct) {
                f32x4 acc = {c2r[ct], c2r[ct], c2r[ct], c2r[ct]};
                acc = __builtin_amdgcn_mfma_f32_16x16x32_bf16(a2, bfrag[ct], acc, 0, 0, 0);
                #pragma unroll
                for (int rg = 0; rg < 4; ++rg)
                    maxv[ct] = fmaxf(maxv[ct], acc[rg]);
            }
        }
        __syncthreads();
    }

    #pragma unroll
    for (int ct = 0; ct < 4; ++ct) {
        float m = maxv[ct];
        m = fmaxf(m, __shfl_xor(m, 16));
        m = fmaxf(m, __shfl_xor(m, 32));
        if (quad == 0) biassh[wave * 64 + ct * 16 + mrow] = m;
    }
    __syncthreads();
    xbb[(size_t)blk * C + tid] = f2bf(x[(size_t)blk * C + tid] + biassh[tid]);
}

// ---- k2m: qkv GEMM; q/k -> qbf (q pre-scaled); v-blocks -> vT via LDS -----
__global__ __launch_bounds__(256) void k2m_qkv(
    const short* __restrict__ xbb, const short* __restrict__ wT,
    short* __restrict__ qbf, short* __restrict__ vT)
{
    __shared__ short tsh[64 * 66];
    const int tid  = threadIdx.x;
    const int lane = tid & 63;
    const int wave = tid >> 6;
    const int quad = lane >> 4;
    const int mrow = lane & 15;
    const int rb = blockIdx.x / 12;
    const int cb = blockIdx.x % 12;
    const int row0 = rb * 64 + wave * 16;
    const int col0 = cb * 64;
    const float osc = (cb < 4) ? SCALE : 1.0f;

    f32x4 acc[4];
    #pragma unroll
    for (int ct = 0; ct < 4; ++ct) acc[ct] = (f32x4){0.f, 0.f, 0.f, 0.f};

    for (int ks = 0; ks < 8; ++ks) {
        bf16x8 afrag = *reinterpret_cast<const bf16x8*>(
            &xbb[(size_t)(row0 + mrow) * 256 + ks * 32 + quad * 8]);
        #pragma unroll
        for (int ct = 0; ct < 4; ++ct) {
            bf16x8 bfrag = *reinterpret_cast<const bf16x8*>(
                &wT[(size_t)(col0 + ct * 16 + mrow) * 256 + ks * 32 + quad * 8]);
            acc[ct] = __builtin_amdgcn_mfma_f32_16x16x32_bf16(afrag, bfrag, acc[ct], 0, 0, 0);
        }
    }

    if (cb < 8) {
        #pragma unroll
        for (int ct = 0; ct < 4; ++ct)
            #pragma unroll
            for (int rg = 0; rg < 4; ++rg)
                qbf[(size_t)(row0 + quad * 4 + rg) * 768 + col0 + ct * 16 + mrow] =
                    f2bf(acc[ct][rg] * osc);
    } else {
        #pragma unroll
        for (int ct = 0; ct < 4; ++ct)
            #pragma unroll
            for (int rg = 0; rg < 4; ++rg)
                tsh[(wave * 16 + quad * 4 + rg) * 66 + ct * 16 + mrow] = f2bf(acc[ct][rg]);
        __syncthreads();
        const int b  = rb >> 3;
        const int s0 = (rb & 7) * 64;
        const int dg = (cb - 8) * 64;
        #pragma unroll
        for (int i = 0; i < 16; ++i) {
            int idx = i * 256 + tid;
            int ci = idx >> 6, rj = idx & 63;
            vT[((size_t)(b * 256 + dg + ci)) * 512 + s0 + rj] = tsh[rj * 66 + ci];
        }
    }
}

// ---- k3f: attention, d-split (no partials, no combine dispatch) -----------
// block = (qt 0..63, dc 0..3). Waves split s (4 x 128) for dots; full softmax
// in-block (cross-wave msh/lsh combine); PV only for this block's 64-d slice.
__global__ __launch_bounds__(256) void k3f_attn(
    const short* __restrict__ qbf, const short* __restrict__ vT,
    float* __restrict__ out)
{
    __shared__ float msh[4][16];
    __shared__ float lsh[4][16];
    __shared__ short psh[16 * 520];   // P [16 q-rows][512 s] bf16, stride 520
    const int tid  = threadIdx.x;
    const int lane = tid & 63;
    const int wave = tid >> 6;
    const int quad = lane >> 4;
    const int mrow = lane & 15;
    const int qt = blockIdx.x >> 2;   // 0..63
    const int dc = blockIdx.x & 3;    // 0..3
    const int b  = qt >> 5;
    const int row0 = qt * 16;

    bf16x8 qf[8];
    {
        const short* qrow = qbf + (size_t)(row0 + mrow) * 768;
        #pragma unroll
        for (int ks = 0; ks < 8; ++ks)
            qf[ks] = *reinterpret_cast<const bf16x8*>(qrow + ks * 32 + quad * 8);
    }

    // dots: wave w owns s-range w*128..w*128+127 (8 s-tiles)
    f32x4 S[8];
    #pragma unroll
    for (int st = 0; st < 8; ++st) {
        f32x4 acc = {0.f, 0.f, 0.f, 0.f};
        const short* krow = qbf +
            (size_t)(b * 512 + wave * 128 + st * 16 + mrow) * 768 + 256;
        #pragma unroll
        for (int ks = 0; ks < 8; ++ks) {
            bf16x8 kf = *reinterpret_cast<const bf16x8*>(krow + ks * 32 + quad * 8);
            acc = __builtin_amdgcn_mfma_f32_16x16x32_bf16(qf[ks], kf, acc, 0, 0, 0);
        }
        S[st] = acc;
    }

    // per-wave row max (rows m=quad*4+rg; cols spread over mrow lanes)
    float mx[4];
    #pragma unroll
    for (int rg = 0; rg < 4; ++rg) {
        mx[rg] = S[0][rg];
        #pragma unroll
        for (int st = 1; st < 8; ++st) mx[rg] = fmaxf(mx[rg], S[st][rg]);
    }
    #pragma unroll
    for (int off = 1; off < 16; off <<= 1)
        #pragma unroll
        for (int rg = 0; rg < 4; ++rg) mx[rg] = fmaxf(mx[rg], __shfl_xor(mx[rg], off));
    if (mrow == 0)
        #pragma unroll
        for (int rg = 0; rg < 4; ++rg) msh[wave][quad * 4 + rg] = mx[rg];
    __syncthreads();

    float M[4], sm[4];
    #pragma unroll
    for (int rg = 0; rg < 4; ++rg) {
        int m = quad * 4 + rg;
        M[rg] = fmaxf(fmaxf(msh[0][m], msh[1][m]), fmaxf(msh[2][m], msh[3][m]));
        sm[rg] = 0.f;
    }
    #pragma unroll
    for (int st = 0; st < 8; ++st)
        #pragma unroll
        for (int rg = 0; rg < 4; ++rg) {
            float e = __expf(S[st][rg] - M[rg]);
            psh[(quad * 4 + rg) * 520 + wave * 128 + st * 16 + mrow] = f2bf(e);
            sm[rg] += e;
        }
    #pragma unroll
    for (int off = 1; off < 16; off <<= 1)
        #pragma unroll
        for (int rg = 0; rg < 4; ++rg) sm[rg] += __shfl_xor(sm[rg], off);
    if (mrow == 0)
        #pragma unroll
        for (int rg = 0; rg < 4; ++rg) lsh[wave][quad * 4 + rg] = sm[rg];
    __syncthreads();

    float linv[4];
    #pragma unroll
    for (int rg = 0; rg < 4; ++rg) {
        int m = quad * 4 + rg;
        linv[rg] = 1.f / (lsh[0][m] + lsh[1][m] + lsh[2][m] + lsh[3][m]);
    }

    // PV: this block's d-slice; wave owns d-tile dc*64 + wave*16
    const short* vbase = vT + ((size_t)(b * 256 + dc * 64 + wave * 16 + mrow)) * 512;
    f32x4 o = {0.f, 0.f, 0.f, 0.f};
    #pragma unroll
    for (int ks = 0; ks < 16; ++ks) {
        bf16x8 pf = *reinterpret_cast<const bf16x8*>(&psh[mrow * 520 + ks * 32 + quad * 8]);
        bf16x8 vf = *reinterpret_cast<const bf16x8*>(vbase + ks * 32 + quad * 8);
        o = __builtin_amdgcn_mfma_f32_16x16x32_bf16(pf, vf, o, 0, 0, 0);
    }
    #pragma unroll
    for (int rg = 0; rg < 4; ++rg)
        out[(size_t)(row0 + quad * 4 + rg) * 256 + dc * 64 + wave * 16 + mrow] =
            o[rg] * linv[rg];
}

extern "C" void kernel_launch(void* const* d_in, const int* in_sizes, int n_in,
                              void* d_out, int out_size, void* d_ws, size_t ws_size,
                              hipStream_t stream) {
    const float* x    = (const float*)d_in[0];
    const float* r    = (const float*)d_in[1];
    const float* w1   = (const float*)d_in[2];
    const float* b1   = (const float*)d_in[3];
    const float* g1   = (const float*)d_in[4];
    const float* be1  = (const float*)d_in[5];
    const float* m1   = (const float*)d_in[6];
    const float* v1   = (const float*)d_in[7];
    const float* w2   = (const float*)d_in[8];
    const float* b2   = (const float*)d_in[9];
    const float* g2   = (const float*)d_in[10];
    const float* be2  = (const float*)d_in[11];
    const float* m2   = (const float*)d_in[12];
    const float* v2   = (const float*)d_in[13];
    const float* wqkv = (const float*)d_in[14];
    float* out = (float*)d_out;

    // ws layout (bytes):
    //   qbf   [1024*768] bf16  @ 0
    //   vT    [2*256*512] bf16 @ 1,572,864
    //   xbb   [1024*256] bf16  @ 2,097,152
    //   wT    [768*256] bf16   @ 2,621,440
    char* ws = (char*)d_ws;
    short*  qbf   = (short*)(ws);
    short*  vT    = (short*)(ws + 1572864);
    short*  xbb   = (short*)(ws + 2097152);
    short*  wT    = (short*)(ws + 2621440);

    k1m_mlp_bias<<<1072, 256, 0, stream>>>(x, r, w1, b1, g1, be1, m1, v1,
                                           w2, b2, g2, be2, m2, v2, wqkv, xbb, wT);
    k2m_qkv<<<192, 256, 0, stream>>>(xbb, wT, qbf, vT);
    k3f_attn<<<256, 256, 0, stream>>>(qbf, vT, out);
}

// Round 9
// 130.533 us; speedup vs baseline: 1.3464x; 1.0057x over previous
//
#include <hip/hip_runtime.h>
#include <hip/hip_bf16.h>

#define T 512
#define C 256
#define D12 12
#define HID 32
#define BN_EPS 1e-5f
#define SCALE 0.0625f

typedef __attribute__((ext_vector_type(8))) short bf16x8;
typedef __attribute__((ext_vector_type(4))) float f32x4;

static __device__ __forceinline__ short f2bf(float f) {
    __hip_bfloat16 h = __float2bfloat16(f);
    return *reinterpret_cast<short*>(&h);
}
static __device__ __forceinline__ float bf2f(short s) {
    __hip_bfloat16 h = *reinterpret_cast<__hip_bfloat16*>(&s);
    return __bfloat162float(h);
}

// ---- k1m: fused TPR MLP + col-max + bias + w_qkv transpose ----------------
// blocks 0..1023: one per (b,s). Layer-1 A-frags straight from global;
// h1sh DOUBLE-BUFFERED -> one barrier per iteration (write h1[p]; barrier;
// read h1[p]; next iter writes h1[1-p], so readers are never overwritten).
// blocks 1024..1071: w_qkv [256][768] f32 -> wT [768][256] bf16 (tiled).
__global__ __launch_bounds__(256) void k1m_mlp_bias(
    const float* __restrict__ x, const float* __restrict__ r,
    const float* __restrict__ w1, const float* __restrict__ b1,
    const float* __restrict__ g1, const float* __restrict__ be1,
    const float* __restrict__ m1, const float* __restrict__ v1,
    const float* __restrict__ w2, const float* __restrict__ b2,
    const float* __restrict__ g2, const float* __restrict__ be2,
    const float* __restrict__ m2, const float* __restrict__ v2,
    const float* __restrict__ wqkv,
    short* __restrict__ xbb, short* __restrict__ wT)
{
    __shared__ short h1sh[2][64 * 40];   // double-buffered [t][h] bf16, stride 40
    __shared__ float biassh[C];
    __shared__ short tsh[64 * 66];

    const int tid  = threadIdx.x;
    const int blk  = blockIdx.x;

    if (blk >= 1024) {   // ---- w_qkv transpose path ----
        const int bid2 = blk - 1024;
        const int d0 = (bid2 / 12) * 64;
        const int e0 = (bid2 % 12) * 64;
        #pragma unroll
        for (int i = 0; i < 16; ++i) {
            int idx = i * 256 + tid;
            int di = idx >> 6, ej = idx & 63;
            tsh[di * 66 + ej] = f2bf(wqkv[(size_t)(d0 + di) * 768 + e0 + ej]);
        }
        __syncthreads();
        #pragma unroll
        for (int i = 0; i < 16; ++i) {
            int idx = i * 256 + tid;
            int ei = idx >> 6, dj = idx & 63;
            wT[(size_t)(e0 + ei) * 256 + d0 + dj] = tsh[dj * 66 + ei];
        }
        return;
    }

    const int lane = tid & 63;
    const int wave = tid >> 6;
    const int quad = lane >> 4;
    const int mrow = lane & 15;

    bf16x8 b1f[2];
    float  c1r[2];
    #pragma unroll
    for (int nt = 0; nt < 2; ++nt) {
        int h = nt * 16 + mrow;
        float s1 = g1[h] * rsqrtf(v1[h] + BN_EPS);
        c1r[nt] = (b1[h] - m1[h]) * s1 + be1[h];
        #pragma unroll
        for (int j = 0; j < 8; ++j) {
            int k = quad * 8 + j;
            b1f[nt][j] = (k < D12) ? f2bf(w1[k * HID + h] * s1) : (short)0;
        }
    }

    bf16x8 bfrag[4];
    float  c2r[4];
    #pragma unroll
    for (int ct = 0; ct < 4; ++ct) {
        int c = wave * 64 + ct * 16 + mrow;
        float s2 = g2[c] * rsqrtf(v2[c] + BN_EPS);
        c2r[ct] = (b2[c] - m2[c]) * s2 + be2[c];
        #pragma unroll
        for (int j = 0; j < 8; ++j) {
            int k = quad * 8 + j;
            bfrag[ct][j] = f2bf(w2[k * C + c] * s2);
        }
    }

    const float* rbase = r + (size_t)blk * T * D12;
    float maxv[4] = {0.f, 0.f, 0.f, 0.f};

    float v[8];
    #pragma unroll
    for (int j = 0; j < 8; ++j) v[j] = 0.f;
    {
        const float* rrow = rbase + (size_t)(wave * 16 + mrow) * D12;
        if (quad == 0) {
            float4 p0 = *reinterpret_cast<const float4*>(rrow);
            float4 p1 = *reinterpret_cast<const float4*>(rrow + 4);
            v[0] = p0.x; v[1] = p0.y; v[2] = p0.z; v[3] = p0.w;
            v[4] = p1.x; v[5] = p1.y; v[6] = p1.z; v[7] = p1.w;
        } else if (quad == 1) {
            float4 p2 = *reinterpret_cast<const float4*>(rrow + 8);
            v[0] = p2.x; v[1] = p2.y; v[2] = p2.z; v[3] = p2.w;
        }
    }

    for (int it = 0; it < 8; ++it) {
        short* hw = &h1sh[it & 1][0];
        bf16x8 af;
        #pragma unroll
        for (int j = 0; j < 8; ++j) af[j] = f2bf(v[j]);
        #pragma unroll
        for (int nt = 0; nt < 2; ++nt) {
            f32x4 a = {c1r[nt], c1r[nt], c1r[nt], c1r[nt]};
            a = __builtin_amdgcn_mfma_f32_16x16x32_bf16(af, b1f[nt], a, 0, 0, 0);
            #pragma unroll
            for (int rg = 0; rg < 4; ++rg)
                hw[(wave * 16 + quad * 4 + rg) * 40 + nt * 16 + mrow] =
                    f2bf(fmaxf(a[rg], 0.f));
        }
        if (it < 7) {
            const float* rrow = rbase + (size_t)((it + 1) * 64 + wave * 16 + mrow) * D12;
            if (quad == 0) {
                float4 p0 = *reinterpret_cast<const float4*>(rrow);
                float4 p1 = *reinterpret_cast<const float4*>(rrow + 4);
                v[0] = p0.x; v[1] = p0.y; v[2] = p0.z; v[3] = p0.w;
                v[4] = p1.x; v[5] = p1.y; v[6] = p1.z; v[7] = p1.w;
            } else if (quad == 1) {
                float4 p2 = *reinterpret_cast<const float4*>(rrow + 8);
                v[0] = p2.x; v[1] = p2.y; v[2] = p2.z; v[3] = p2.w;
            }
        }
        __syncthreads();   // h1[p] writes visible; next iter writes h1[1-p]
        #pragma unroll
        for (int rt = 0; rt < 4; ++rt) {
            bf16x8 a2 = *reinterpret_cast<const bf16x8*>(
                &hw[(rt * 16 + mrow) * 40 + quad * 8]);
            #pragma unroll
            for (int ct = 0; ct < 4; ++ct) {
                f32x4 acc = {c2r[ct], c2r[ct], c2r[ct], c2r[ct]};
                acc = __builtin_amdgcn_mfma_f32_16x16x32_bf16(a2, bfrag[ct], acc, 0, 0, 0);
                #pragma unroll
                for (int rg = 0; rg < 4; ++rg)
                    maxv[ct] = fmaxf(maxv[ct], acc[rg]);
            }
        }
    }

    #pragma unroll
    for (int ct = 0; ct < 4; ++ct) {
        float m = maxv[ct];
        m = fmaxf(m, __shfl_xor(m, 16));
        m = fmaxf(m, __shfl_xor(m, 32));
        if (quad == 0) biassh[wave * 64 + ct * 16 + mrow] = m;
    }
    __syncthreads();
    xbb[(size_t)blk * C + tid] = f2bf(x[(size_t)blk * C + tid] + biassh[tid]);
}

// ---- k2m: qkv GEMM; q/k -> qbf (q pre-scaled); v-blocks -> vT via LDS -----
__global__ __launch_bounds__(256) void k2m_qkv(
    const short* __restrict__ xbb, const short* __restrict__ wT,
    short* __restrict__ qbf, short* __restrict__ vT)
{
    __shared__ short tsh[64 * 66];
    const int tid  = threadIdx.x;
    const int lane = tid & 63;
    const int wave = tid >> 6;
    const int quad = lane >> 4;
    const int mrow = lane & 15;
    const int rb = blockIdx.x / 12;
    const int cb = blockIdx.x % 12;
    const int row0 = rb * 64 + wave * 16;
    const int col0 = cb * 64;
    const float osc = (cb < 4) ? SCALE : 1.0f;

    f32x4 acc[4];
    #pragma unroll
    for (int ct = 0; ct < 4; ++ct) acc[ct] = (f32x4){0.f, 0.f, 0.f, 0.f};

    for (int ks = 0; ks < 8; ++ks) {
        bf16x8 afrag = *reinterpret_cast<const bf16x8*>(
            &xbb[(size_t)(row0 + mrow) * 256 + ks * 32 + quad * 8]);
        #pragma unroll
        for (int ct = 0; ct < 4; ++ct) {
            bf16x8 bfrag = *reinterpret_cast<const bf16x8*>(
                &wT[(size_t)(col0 + ct * 16 + mrow) * 256 + ks * 32 + quad * 8]);
            acc[ct] = __builtin_amdgcn_mfma_f32_16x16x32_bf16(afrag, bfrag, acc[ct], 0, 0, 0);
        }
    }

    if (cb < 8) {
        #pragma unroll
        for (int ct = 0; ct < 4; ++ct)
            #pragma unroll
            for (int rg = 0; rg < 4; ++rg)
                qbf[(size_t)(row0 + quad * 4 + rg) * 768 + col0 + ct * 16 + mrow] =
                    f2bf(acc[ct][rg] * osc);
    } else {
        #pragma unroll
        for (int ct = 0; ct < 4; ++ct)
            #pragma unroll
            for (int rg = 0; rg < 4; ++rg)
                tsh[(wave * 16 + quad * 4 + rg) * 66 + ct * 16 + mrow] = f2bf(acc[ct][rg]);
        __syncthreads();
        const int b  = rb >> 3;
        const int s0 = (rb & 7) * 64;
        const int dg = (cb - 8) * 64;
        #pragma unroll
        for (int i = 0; i < 16; ++i) {
            int idx = i * 256 + tid;
            int ci = idx >> 6, rj = idx & 63;
            vT[((size_t)(b * 256 + dg + ci)) * 512 + s0 + rj] = tsh[rj * 66 + ci];
        }
    }
}

// ---- k3a: flash attention partials via MFMA (po stored bf16) --------------
__global__ __launch_bounds__(256) void k3a_attn(
    const short* __restrict__ qbf, const short* __restrict__ vT,
    short* __restrict__ po, float2* __restrict__ stats)
{
    __shared__ float msh[4][16];
    __shared__ float lsh[4][16];
    __shared__ short psh[16 * 136];
    const int tid  = threadIdx.x;
    const int lane = tid & 63;
    const int wave = tid >> 6;
    const int quad = lane >> 4;
    const int mrow = lane & 15;
    const int qt = blockIdx.x >> 2;
    const int sc = blockIdx.x & 3;
    const int b  = qt >> 5;
    const int row0  = qt * 16;
    const int srow0 = b * 512 + sc * 128;

    bf16x8 qf[8];
    {
        const short* qrow = qbf + (size_t)(row0 + mrow) * 768;
        #pragma unroll
        for (int ks = 0; ks < 8; ++ks)
            qf[ks] = *reinterpret_cast<const bf16x8*>(qrow + ks * 32 + quad * 8);
    }

    f32x4 S[2];
    #pragma unroll
    for (int st = 0; st < 2; ++st) {
        f32x4 acc = {0.f, 0.f, 0.f, 0.f};
        const short* krow = qbf + (size_t)(srow0 + wave * 32 + st * 16 + mrow) * 768 + 256;
        #pragma unroll
        for (int ks = 0; ks < 8; ++ks) {
            bf16x8 kf = *reinterpret_cast<const bf16x8*>(krow + ks * 32 + quad * 8);
            acc = __builtin_amdgcn_mfma_f32_16x16x32_bf16(qf[ks], kf, acc, 0, 0, 0);
        }
        S[st] = acc;
    }

    float mx[4];
    #pragma unroll
    for (int rg = 0; rg < 4; ++rg) mx[rg] = fmaxf(S[0][rg], S[1][rg]);
    #pragma unroll
    for (int off = 1; off < 16; off <<= 1)
        #pragma unroll
        for (int rg = 0; rg < 4; ++rg) mx[rg] = fmaxf(mx[rg], __shfl_xor(mx[rg], off));
    if (mrow == 0)
        #pragma unroll
        for (int rg = 0; rg < 4; ++rg) msh[wave][quad * 4 + rg] = mx[rg];
    __syncthreads();

    float M[4], sm[4];
    #pragma unroll
    for (int rg = 0; rg < 4; ++rg) {
        int m = quad * 4 + rg;
        M[rg] = fmaxf(fmaxf(msh[0][m], msh[1][m]), fmaxf(msh[2][m], msh[3][m]));
    }
    float ex[2][4];
    #pragma unroll
    for (int st = 0; st < 2; ++st)
        #pragma unroll
        for (int rg = 0; rg < 4; ++rg) ex[st][rg] = __expf(S[st][rg] - M[rg]);
    #pragma unroll
    for (int rg = 0; rg < 4; ++rg) sm[rg] = ex[0][rg] + ex[1][rg];
    #pragma unroll
    for (int off = 1; off < 16; off <<= 1)
        #pragma unroll
        for (int rg = 0; rg < 4; ++rg) sm[rg] += __shfl_xor(sm[rg], off);
    if (mrow == 0)
        #pragma unroll
        for (int rg = 0; rg < 4; ++rg) lsh[wave][quad * 4 + rg] = sm[rg];
    #pragma unroll
    for (int st = 0; st < 2; ++st)
        #pragma unroll
        for (int rg = 0; rg < 4; ++rg)
            psh[(quad * 4 + rg) * 136 + wave * 32 + st * 16 + mrow] = f2bf(ex[st][rg]);
    __syncthreads();

    if (wave == 0 && mrow == 0) {
        #pragma unroll
        for (int rg = 0; rg < 4; ++rg) {
            int m = quad * 4 + rg;
            float l = lsh[0][m] + lsh[1][m] + lsh[2][m] + lsh[3][m];
            stats[blockIdx.x * 16 + m] = make_float2(M[rg], l);
        }
    }

    const short* vbase = vT + (size_t)b * 256 * 512;
    f32x4 o[4];
    #pragma unroll
    for (int i = 0; i < 4; ++i) o[i] = (f32x4){0.f, 0.f, 0.f, 0.f};
    #pragma unroll
    for (int ks = 0; ks < 4; ++ks) {
        bf16x8 pf = *reinterpret_cast<const bf16x8*>(&psh[mrow * 136 + ks * 32 + quad * 8]);
        #pragma unroll
        for (int i = 0; i < 4; ++i) {
            int d0 = (wave * 4 + i) * 16;
            bf16x8 vf = *reinterpret_cast<const bf16x8*>(
                vbase + (size_t)(d0 + mrow) * 512 + sc * 128 + ks * 32 + quad * 8);
            o[i] = __builtin_amdgcn_mfma_f32_16x16x32_bf16(pf, vf, o[i], 0, 0, 0);
        }
    }
    #pragma unroll
    for (int i = 0; i < 4; ++i)
        #pragma unroll
        for (int rg = 0; rg < 4; ++rg)
            po[((size_t)blockIdx.x * 16 + quad * 4 + rg) * 256 + (wave * 4 + i) * 16 + mrow] =
                f2bf(o[i][rg]);
}

// ---- k3b: combine 4 chunk partials per row (bf16 po) ----------------------
__global__ __launch_bounds__(256) void k3b_combine(
    const short* __restrict__ po, const float2* __restrict__ stats,
    float* __restrict__ out)
{
    const int row = blockIdx.x;
    const int qt = row >> 4, m = row & 15;
    const int c = threadIdx.x;
    float2 s0 = stats[(qt * 4 + 0) * 16 + m];
    float2 s1 = stats[(qt * 4 + 1) * 16 + m];
    float2 s2 = stats[(qt * 4 + 2) * 16 + m];
    float2 s3 = stats[(qt * 4 + 3) * 16 + m];
    float M = fmaxf(fmaxf(s0.x, s1.x), fmaxf(s2.x, s3.x));
    float a0 = __expf(s0.x - M), a1 = __expf(s1.x - M);
    float a2 = __expf(s2.x - M), a3 = __expf(s3.x - M);
    float inv = 1.f / (a0 * s0.y + a1 * s1.y + a2 * s2.y + a3 * s3.y);
    float acc = a0 * bf2f(po[((size_t)(qt * 4 + 0) * 16 + m) * 256 + c])
              + a1 * bf2f(po[((size_t)(qt * 4 + 1) * 16 + m) * 256 + c])
              + a2 * bf2f(po[((size_t)(qt * 4 + 2) * 16 + m) * 256 + c])
              + a3 * bf2f(po[((size_t)(qt * 4 + 3) * 16 + m) * 256 + c]);
    out[(size_t)row * 256 + c] = acc * inv;
}

extern "C" void kernel_launch(void* const* d_in, const int* in_sizes, int n_in,
                              void* d_out, int out_size, void* d_ws, size_t ws_size,
                              hipStream_t stream) {
    const float* x    = (const float*)d_in[0];
    const float* r    = (const float*)d_in[1];
    const float* w1   = (const float*)d_in[2];
    const float* b1   = (const float*)d_in[3];
    const float* g1   = (const float*)d_in[4];
    const float* be1  = (const float*)d_in[5];
    const float* m1   = (const float*)d_in[6];
    const float* v1   = (const float*)d_in[7];
    const float* w2   = (const float*)d_in[8];
    const float* b2   = (const float*)d_in[9];
    const float* g2   = (const float*)d_in[10];
    const float* be2  = (const float*)d_in[11];
    const float* m2   = (const float*)d_in[12];
    const float* v2   = (const float*)d_in[13];
    const float* wqkv = (const float*)d_in[14];
    float* out = (float*)d_out;

    // ws layout (bytes):
    //   qbf   [1024*768] bf16   @ 0
    //   vT    [2*256*512] bf16  @ 1,572,864
    //   xbb   [1024*256] bf16   @ 2,097,152
    //   wT    [768*256] bf16    @ 2,621,440
    //   po    [256*16*256] bf16 @ 3,014,656  (2,097,152)
    //   stats [256*16] float2   @ 5,111,808
    char* ws = (char*)d_ws;
    short*  qbf   = (short*)(ws);
    short*  vT    = (short*)(ws + 1572864);
    short*  xbb   = (short*)(ws + 2097152);
    short*  wT    = (short*)(ws + 2621440);
    short*  po    = (short*)(ws + 3014656);
    float2* stats = (float2*)(ws + 5111808);

    k1m_mlp_bias<<<1072, 256, 0, stream>>>(x, r, w1, b1, g1, be1, m1, v1,
                                           w2, b2, g2, be2, m2, v2, wqkv, xbb, wT);
    k2m_qkv<<<192, 256, 0, stream>>>(xbb, wT, qbf, vT);
    k3a_attn<<<256, 256, 0, stream>>>(qbf, vT, po, stats);
    k3b_combine<<<1024, 256, 0, stream>>>(po, stats, out);
}